// Round 3
// baseline (373.680 us; speedup 1.0000x reference)
//
#include <hip/hip_runtime.h>
#include <math.h>

#define HDIM 1536
#define NUM_HEADS 12
#define NUM_KV 2
#define HEAD_DIM 128
#define GQA_REP 6
#define MAX_CACHE 131072
#define SCALE 0.08838834764831845f   // 128^-0.5

// workspace layout (float offsets)
#define WS_Q    0                     // 1536 floats (pre-scaled q)
#define WS_OUT  2048                  // 1536 floats (attention out, flat)
#define WS_L2   4096                  // 12*32*132 = 50688 floats
#define WS_PART 65536                 // 2048*6*132 = 1622016 floats
#define REC 132                       // per-partial record: [m, l, pad, pad, acc(128)]

#define UNITS_PER_G 1024              // 131072 / 128 positions per block-unit
#define NEG_BIG (-1.0e30f)
#define MASK_NEG (-1.0e38f)

// ---------------------------------------------------------------------------
// Kernel 1: fused QKV projection. 2048 rows, one row per wave.
// ---------------------------------------------------------------------------
__global__ __launch_bounds__(256) void proj_qkv(
    const float* __restrict__ x, const float* __restrict__ Wq,
    const float* __restrict__ Wk, const float* __restrict__ Wv,
    float* __restrict__ kv_k, float* __restrict__ kv_v,
    const int* __restrict__ pos_p, float* __restrict__ ws)
{
    int r    = (blockIdx.x * 256 + threadIdx.x) >> 6;   // 0..2047
    int lane = threadIdx.x & 63;

    const float* Wrow;
    if (r < HDIM)            Wrow = Wq + (size_t)r * HDIM;
    else if (r < HDIM + 256) Wrow = Wk + (size_t)(r - HDIM) * HDIM;
    else                     Wrow = Wv + (size_t)(r - HDIM - 256) * HDIM;

    const float4* w4 = (const float4*)Wrow;
    const float4* x4 = (const float4*)x;
    float sum = 0.f;
#pragma unroll
    for (int it = 0; it < 6; ++it) {
        float4 a = w4[lane + 64 * it];
        float4 b = x4[lane + 64 * it];
        sum += a.x * b.x + a.y * b.y + a.z * b.z + a.w * b.w;
    }
#pragma unroll
    for (int off = 32; off >= 1; off >>= 1) sum += __shfl_xor(sum, off);

    if (lane == 0) {
        if (r < HDIM) {
            ws[WS_Q + r] = sum * SCALE;
        } else {
            int pos = *pos_p;
            if (r < HDIM + 256) {
                int j = r - HDIM; int g = j >> 7, d = j & 127;
                kv_k[((size_t)g * MAX_CACHE + pos) * HEAD_DIM + d] = sum;
            } else {
                int j = r - HDIM - 256; int g = j >> 7, d = j & 127;
                kv_v[((size_t)g * MAX_CACHE + pos) * HEAD_DIM + d] = sum;
            }
        }
    }
}

// ---------------------------------------------------------------------------
// Kernel 2: flash-decode. Block = 4 waves x 32 positions = 128 positions of
// one KV group. Within a wave: quarter-wave per position (lane = sub*16 + j,
// sub = position within the iteration's 4, j = dim-chunk). Lane j owns
// float4 chunks {j, j+16} (dims [4j..4j+4) and [64+4j..64+4j+4)).
// 4 positions per iteration, 8 iterations, 1-iteration register prefetch
// (4 KB in flight per wave). Quarter merge via shfl_xor 16/32; wave partials
// merged across the block in LDS; 2048 records out (combine1/2 unchanged).
// ---------------------------------------------------------------------------
__global__ __launch_bounds__(256, 3) void attn_decode(
    const float* __restrict__ kv_k, const float* __restrict__ kv_v,
    const int* __restrict__ pos_p, float* __restrict__ ws)
{
    __shared__ float lds[4][GQA_REP][REC];

    int b    = blockIdx.x;          // 0..2047
    int g    = b >> 10;             // kv group
    int ublk = b & 1023;            // unit (block) within group
    int wid  = threadIdx.x >> 6;    // wave 0..3
    int lane = threadIdx.x & 63;
    int sub  = lane >> 4;           // position slot 0..3 within iteration
    int j    = lane & 15;           // dim-chunk 0..15

    int seq_len = *pos_p + 1;
    if (seq_len > MAX_CACHE) seq_len = MAX_CACHE;

    // q fragments (pre-scaled): lane j holds chunks {j, j+16} of each head
    const float* qb = ws + WS_Q + g * (GQA_REP * HEAD_DIM);
    float4 qa[GQA_REP], qc[GQA_REP];
#pragma unroll
    for (int r = 0; r < GQA_REP; ++r) {
        const float4* q4 = (const float4*)(qb + r * HEAD_DIM);
        qa[r] = q4[j];
        qc[r] = q4[j + 16];
    }

    float  m[GQA_REP], l[GQA_REP];
    float4 accA[GQA_REP], accB[GQA_REP];
#pragma unroll
    for (int r = 0; r < GQA_REP; ++r) {
        m[r] = NEG_BIG; l[r] = 0.f;
        accA[r].x = accA[r].y = accA[r].z = accA[r].w = 0.f;
        accB[r].x = accB[r].y = accB[r].z = accB[r].w = 0.f;
    }

    int wbase = ublk * 128 + wid * 32;       // this wave's 32 positions
    const float4* Kp = (const float4*)(kv_k + ((size_t)g * MAX_CACHE + wbase) * HEAD_DIM);
    const float4* Vp = (const float4*)(kv_v + ((size_t)g * MAX_CACHE + wbase) * HEAD_DIM);
    int f0 = sub * 32 + j;                   // float4 index: pos sub, chunk j

    float4 Ka = Kp[f0], Kb4 = Kp[f0 + 16];
    float4 Va = Vp[f0], Vb4 = Vp[f0 + 16];

#pragma unroll
    for (int i = 0; i < 8; ++i) {
        float4 Kna, Knb, Vna, Vnb;
        if (i < 7) {                 // register prefetch of next iteration
            int n = f0 + (i + 1) * 128;
            Kna = Kp[n]; Knb = Kp[n + 16];
            Vna = Vp[n]; Vnb = Vp[n + 16];
        }
        int p = wbase + i * 4 + sub;
        float maskadd = (p < seq_len) ? 0.f : MASK_NEG;

#pragma unroll
        for (int r = 0; r < GQA_REP; ++r) {
            float sr = Ka.x * qa[r].x + Ka.y * qa[r].y + Ka.z * qa[r].z + Ka.w * qa[r].w
                     + Kb4.x * qc[r].x + Kb4.y * qc[r].y + Kb4.z * qc[r].z + Kb4.w * qc[r].w;
#pragma unroll
            for (int off = 8; off >= 1; off >>= 1) sr += __shfl_xor(sr, off);
            float s = sr + maskadd;

            float mn    = fmaxf(m[r], s);
            float alpha = __expf(m[r] - mn);
            float pw    = __expf(s - mn);
            l[r] = l[r] * alpha + pw;
            accA[r].x = accA[r].x * alpha + pw * Va.x;
            accA[r].y = accA[r].y * alpha + pw * Va.y;
            accA[r].z = accA[r].z * alpha + pw * Va.z;
            accA[r].w = accA[r].w * alpha + pw * Va.w;
            accB[r].x = accB[r].x * alpha + pw * Vb4.x;
            accB[r].y = accB[r].y * alpha + pw * Vb4.y;
            accB[r].z = accB[r].z * alpha + pw * Vb4.z;
            accB[r].w = accB[r].w * alpha + pw * Vb4.w;
            m[r] = mn;
        }
        Ka = Kna; Kb4 = Knb; Va = Vna; Vb4 = Vnb;
    }

    // merge the 4 quarters (lane bits 4,5): shfl_xor 16 then 32
#pragma unroll
    for (int r = 0; r < GQA_REP; ++r) {
#pragma unroll
        for (int off = 16; off <= 32; off <<= 1) {
            float mo = __shfl_xor(m[r], off);
            float lo = __shfl_xor(l[r], off);
            float4 aoA, aoB;
            aoA.x = __shfl_xor(accA[r].x, off); aoA.y = __shfl_xor(accA[r].y, off);
            aoA.z = __shfl_xor(accA[r].z, off); aoA.w = __shfl_xor(accA[r].w, off);
            aoB.x = __shfl_xor(accB[r].x, off); aoB.y = __shfl_xor(accB[r].y, off);
            aoB.z = __shfl_xor(accB[r].z, off); aoB.w = __shfl_xor(accB[r].w, off);
            float M  = fmaxf(m[r], mo);
            float a0 = __expf(m[r] - M);
            float a1 = __expf(mo   - M);
            l[r] = l[r] * a0 + lo * a1;
            accA[r].x = accA[r].x * a0 + aoA.x * a1;
            accA[r].y = accA[r].y * a0 + aoA.y * a1;
            accA[r].z = accA[r].z * a0 + aoA.z * a1;
            accA[r].w = accA[r].w * a0 + aoA.w * a1;
            accB[r].x = accB[r].x * a0 + aoB.x * a1;
            accB[r].y = accB[r].y * a0 + aoB.y * a1;
            accB[r].z = accB[r].z * a0 + aoB.z * a1;
            accB[r].w = accB[r].w * a0 + aoB.w * a1;
            m[r] = M;
        }
        // park wave partial in LDS (lanes 0..15 hold the merged result)
        if (lane < 16) {
            ((float4*)&lds[wid][r][4])[j]      = accA[r];
            ((float4*)&lds[wid][r][4])[j + 16] = accB[r];
        }
        if (lane == 0) { lds[wid][r][0] = m[r]; lds[wid][r][1] = l[r]; }
    }
    __syncthreads();

    // cross-wave merge: wave `wid` handles heads r = wid, wid+4
    for (int r = wid; r < GQA_REP; r += 4) {
        float m0 = lds[0][r][0], m1 = lds[1][r][0];
        float m2 = lds[2][r][0], m3 = lds[3][r][0];
        float M = fmaxf(fmaxf(m0, m1), fmaxf(m2, m3));
        float w0 = __expf(m0 - M), w1 = __expf(m1 - M);
        float w2 = __expf(m2 - M), w3 = __expf(m3 - M);
        float L = lds[0][r][1] * w0 + lds[1][r][1] * w1
                + lds[2][r][1] * w2 + lds[3][r][1] * w3;

        float2 a0v = ((const float2*)&lds[0][r][4])[lane];
        float2 a1v = ((const float2*)&lds[1][r][4])[lane];
        float2 a2v = ((const float2*)&lds[2][r][4])[lane];
        float2 a3v = ((const float2*)&lds[3][r][4])[lane];
        float2 a;
        a.x = a0v.x * w0 + a1v.x * w1 + a2v.x * w2 + a3v.x * w3;
        a.y = a0v.y * w0 + a1v.y * w1 + a2v.y * w2 + a3v.y * w3;

        float* rec = ws + WS_PART + ((size_t)(g * UNITS_PER_G + ublk) * GQA_REP + r) * REC;
        ((float2*)(rec + 4))[lane] = a;
        if (lane == 0) { rec[0] = M; rec[1] = L; }
    }
}

// ---------------------------------------------------------------------------
// Kernel 3: combine stage 1 — 12 heads x 32 slabs; each block merges 32 units.
// ---------------------------------------------------------------------------
__global__ __launch_bounds__(64) void combine1(float* __restrict__ ws)
{
    int b  = blockIdx.x;          // 0..383
    int hh = b >> 5;              // head 0..11
    int s  = b & 31;              // slab
    int g = hh / GQA_REP, r = hh % GQA_REP;
    int t  = threadIdx.x;         // 0..63
    int um = t & 31;

    const float* base = ws + WS_PART +
        ((size_t)(g * UNITS_PER_G + s * 32) * GQA_REP + r) * REC;
    const float* rec = base + (size_t)um * GQA_REP * REC;
    float mu = rec[0], lu = rec[1];

    float M = mu;
#pragma unroll
    for (int off = 16; off >= 1; off >>= 1) M = fmaxf(M, __shfl_xor(M, off));
    float w = __expf(mu - M);
    float L = lu * w;
#pragma unroll
    for (int off = 16; off >= 1; off >>= 1) L += __shfl_xor(L, off);

    float2 a; a.x = 0.f; a.y = 0.f;      // dims 2t, 2t+1
    for (int uu = 0; uu < 32; ++uu) {
        float wu = __shfl(w, uu);
        float2 av = ((const float2*)(base + (size_t)uu * GQA_REP * REC + 4))[t];
        a.x += wu * av.x;
        a.y += wu * av.y;
    }
    float* orec = ws + WS_L2 + (size_t)(hh * 32 + s) * REC;
    ((float2*)(orec + 4))[t] = a;
    if (t == 0) { orec[0] = M; orec[1] = L; }
}

// ---------------------------------------------------------------------------
// Kernel 4: combine stage 2 — 12 heads; merge 32 slab records, write out vec.
// ---------------------------------------------------------------------------
__global__ __launch_bounds__(64) void combine2(float* __restrict__ ws)
{
    int hh = blockIdx.x;          // 0..11
    int t  = threadIdx.x;
    int um = t & 31;

    const float* base = ws + WS_L2 + (size_t)(hh * 32) * REC;
    const float* rec  = base + (size_t)um * REC;
    float mu = rec[0], lu = rec[1];

    float M = mu;
#pragma unroll
    for (int off = 16; off >= 1; off >>= 1) M = fmaxf(M, __shfl_xor(M, off));
    float w = __expf(mu - M);
    float L = lu * w;
#pragma unroll
    for (int off = 16; off >= 1; off >>= 1) L += __shfl_xor(L, off);

    float2 a; a.x = 0.f; a.y = 0.f;
    for (int uu = 0; uu < 32; ++uu) {
        float wu = __shfl(w, uu);
        float2 av = ((const float2*)(base + (size_t)uu * REC + 4))[t];
        a.x += wu * av.x;
        a.y += wu * av.y;
    }
    float invL = 1.f / L;
    ws[WS_OUT + hh * HEAD_DIM + 2 * t]     = a.x * invL;
    ws[WS_OUT + hh * HEAD_DIM + 2 * t + 1] = a.y * invL;
}

// ---------------------------------------------------------------------------
// Kernel 5: output projection y = Wo @ out. One row per wave.
// ---------------------------------------------------------------------------
__global__ __launch_bounds__(256) void proj_out(
    const float* __restrict__ Wo, const float* __restrict__ ws,
    float* __restrict__ y)
{
    int r    = (blockIdx.x * 256 + threadIdx.x) >> 6;   // 0..1535
    int lane = threadIdx.x & 63;
    const float4* w4 = (const float4*)(Wo + (size_t)r * HDIM);
    const float4* o4 = (const float4*)(ws + WS_OUT);
    float sum = 0.f;
#pragma unroll
    for (int it = 0; it < 6; ++it) {
        float4 a = w4[lane + 64 * it];
        float4 b = o4[lane + 64 * it];
        sum += a.x * b.x + a.y * b.y + a.z * b.z + a.w * b.w;
    }
#pragma unroll
    for (int off = 32; off >= 1; off >>= 1) sum += __shfl_xor(sum, off);
    if (lane == 0) y[r] = sum;
}

// ---------------------------------------------------------------------------
extern "C" void kernel_launch(void* const* d_in, const int* in_sizes, int n_in,
                              void* d_out, int out_size, void* d_ws, size_t ws_size,
                              hipStream_t stream) {
    const float* x   = (const float*)d_in[0];
    const float* Wq  = (const float*)d_in[1];
    const float* Wk  = (const float*)d_in[2];
    const float* Wv  = (const float*)d_in[3];
    const float* Wo  = (const float*)d_in[4];
    float*       kvk = (float*)d_in[5];
    float*       kvv = (float*)d_in[6];
    const int*   pos = (const int*)d_in[7];
    float* ws = (float*)d_ws;
    float* y  = (float*)d_out;

    proj_qkv   <<<512,  256, 0, stream>>>(x, Wq, Wk, Wv, kvk, kvv, pos, ws);
    attn_decode<<<2048, 256, 0, stream>>>(kvk, kvv, pos, ws);
    combine1   <<<384,   64, 0, stream>>>(ws);
    combine2   <<< 12,   64, 0, stream>>>(ws);
    proj_out   <<<384,  256, 0, stream>>>(Wo, ws, y);
}

// Round 4
// 322.156 us; speedup vs baseline: 1.1599x; 1.1599x over previous
//
#include <hip/hip_runtime.h>
#include <math.h>

#define HDIM 1536
#define NUM_HEADS 12
#define NUM_KV 2
#define HEAD_DIM 128
#define GQA_REP 6
#define MAX_CACHE 131072
#define SCALE 0.08838834764831845f   // 128^-0.5

// workspace layout (float offsets)
#define WS_Q    0                     // 1536 floats (pre-scaled q)
#define WS_OUT  2048                  // 1536 floats (attention out, flat)
#define WS_L2   4096                  // 12*32*132 = 50688 floats
#define WS_PART 65536                 // 2048*6*132 = 1622016 floats
#define REC 132                       // per-partial record: [m, l, pad, pad, acc(128)]

#define UNITS_PER_G 1024              // 131072 / 128 positions per block-unit
#define NEG_BIG (-1.0e30f)
#define MASK_NEG (-1.0e38f)

// ---------------------------------------------------------------------------
// Kernel 1: fused QKV projection. 2048 rows, one row per wave.
// ---------------------------------------------------------------------------
__global__ __launch_bounds__(256) void proj_qkv(
    const float* __restrict__ x, const float* __restrict__ Wq,
    const float* __restrict__ Wk, const float* __restrict__ Wv,
    float* __restrict__ kv_k, float* __restrict__ kv_v,
    const int* __restrict__ pos_p, float* __restrict__ ws)
{
    int r    = (blockIdx.x * 256 + threadIdx.x) >> 6;   // 0..2047
    int lane = threadIdx.x & 63;

    const float* Wrow;
    if (r < HDIM)            Wrow = Wq + (size_t)r * HDIM;
    else if (r < HDIM + 256) Wrow = Wk + (size_t)(r - HDIM) * HDIM;
    else                     Wrow = Wv + (size_t)(r - HDIM - 256) * HDIM;

    const float4* w4 = (const float4*)Wrow;
    const float4* x4 = (const float4*)x;
    float sum = 0.f;
#pragma unroll
    for (int it = 0; it < 6; ++it) {
        float4 a = w4[lane + 64 * it];
        float4 b = x4[lane + 64 * it];
        sum += a.x * b.x + a.y * b.y + a.z * b.z + a.w * b.w;
    }
#pragma unroll
    for (int off = 32; off >= 1; off >>= 1) sum += __shfl_xor(sum, off);

    if (lane == 0) {
        if (r < HDIM) {
            ws[WS_Q + r] = sum * SCALE;
        } else {
            int pos = *pos_p;
            if (r < HDIM + 256) {
                int j = r - HDIM; int g = j >> 7, d = j & 127;
                kv_k[((size_t)g * MAX_CACHE + pos) * HEAD_DIM + d] = sum;
            } else {
                int j = r - HDIM - 256; int g = j >> 7, d = j & 127;
                kv_v[((size_t)g * MAX_CACHE + pos) * HEAD_DIM + d] = sum;
            }
        }
    }
}

// ---------------------------------------------------------------------------
// Kernel 2: flash-decode. Block = 4 waves x 32 positions = 128 positions of
// one KV group. Half-wave h handles positions 4t+h and 4t+2+h each
// super-iteration (4 positions / super-iter, 8 super-iters). Lane j (0..31)
// owns float4 chunk j (dims 4j..4j+3). Online-softmax update batched over
// the two position-pairs: one rescale per head per super-iteration.
// Register prefetch one super-iteration deep (4 KB/wave in flight).
// __launch_bounds__(256,4): 128-VGPR budget — fits ~110 live regs, no spill.
// ---------------------------------------------------------------------------
__global__ __launch_bounds__(256, 4) void attn_decode(
    const float* __restrict__ kv_k, const float* __restrict__ kv_v,
    const int* __restrict__ pos_p, float* __restrict__ ws)
{
    __shared__ float lds[4][GQA_REP][REC];

    int b    = blockIdx.x;          // 0..2047
    int g    = b >> 10;             // kv group
    int ublk = b & 1023;            // unit (block) within group
    int wid  = threadIdx.x >> 6;    // wave 0..3
    int lane = threadIdx.x & 63;
    int h    = lane >> 5;           // half (position low bit)
    int j    = lane & 31;           // float4 chunk within head_dim

    int seq_len = *pos_p + 1;
    if (seq_len > MAX_CACHE) seq_len = MAX_CACHE;

    // q fragments (pre-scaled)
    const float* qb = ws + WS_Q + g * (GQA_REP * HEAD_DIM);
    float4 q[GQA_REP];
#pragma unroll
    for (int r = 0; r < GQA_REP; ++r)
        q[r] = ((const float4*)(qb + r * HEAD_DIM))[j];

    float  m[GQA_REP], l[GQA_REP];
    float4 acc[GQA_REP];
#pragma unroll
    for (int r = 0; r < GQA_REP; ++r) {
        m[r] = NEG_BIG; l[r] = 0.f;
        acc[r].x = acc[r].y = acc[r].z = acc[r].w = 0.f;
    }

    int wbase = ublk * 128 + wid * 32;       // this wave's 32 positions
    const float4* Kp = (const float4*)(kv_k + ((size_t)g * MAX_CACHE + wbase) * HEAD_DIM);
    const float4* Vp = (const float4*)(kv_v + ((size_t)g * MAX_CACHE + wbase) * HEAD_DIM);
    int i0 = h * 32 + j;                     // float4 idx: pos-offset h, chunk j

    float4 KA = Kp[i0],      KB = Kp[i0 + 64];
    float4 VA = Vp[i0],      VB = Vp[i0 + 64];

    for (int t = 0; t < 8; ++t) {
        float4 KAn, KBn, VAn, VBn;
        if (t < 7) {                 // prefetch next super-iteration
            int n = i0 + (t + 1) * 128;
            KAn = Kp[n]; KBn = Kp[n + 64];
            VAn = Vp[n]; VBn = Vp[n + 64];
        }
        int pA = wbase + 4 * t + h;          // position for pair A
        float maskA = (pA     < seq_len) ? 0.f : MASK_NEG;
        float maskB = (pA + 2 < seq_len) ? 0.f : MASK_NEG;

#pragma unroll
        for (int r = 0; r < GQA_REP; ++r) {
            float sA = KA.x * q[r].x + KA.y * q[r].y + KA.z * q[r].z + KA.w * q[r].w;
            float sB = KB.x * q[r].x + KB.y * q[r].y + KB.z * q[r].z + KB.w * q[r].w;
#pragma unroll
            for (int off = 16; off >= 1; off >>= 1) {
                sA += __shfl_xor(sA, off);
                sB += __shfl_xor(sB, off);
            }
            sA += maskA; sB += maskB;

            float mn    = fmaxf(m[r], fmaxf(sA, sB));
            float alpha = __expf(m[r] - mn);
            float pa    = __expf(sA - mn);
            float pb    = __expf(sB - mn);
            l[r] = l[r] * alpha + pa + pb;
            acc[r].x = acc[r].x * alpha + pa * VA.x + pb * VB.x;
            acc[r].y = acc[r].y * alpha + pa * VA.y + pb * VB.y;
            acc[r].z = acc[r].z * alpha + pa * VA.z + pb * VB.z;
            acc[r].w = acc[r].w * alpha + pa * VA.w + pb * VB.w;
            m[r] = mn;
        }
        KA = KAn; KB = KBn; VA = VAn; VB = VBn;
    }

    // merge the two halves, park wave partial in LDS
#pragma unroll
    for (int r = 0; r < GQA_REP; ++r) {
        float mo = __shfl_xor(m[r], 32);
        float lo = __shfl_xor(l[r], 32);
        float4 ao;
        ao.x = __shfl_xor(acc[r].x, 32);
        ao.y = __shfl_xor(acc[r].y, 32);
        ao.z = __shfl_xor(acc[r].z, 32);
        ao.w = __shfl_xor(acc[r].w, 32);
        float M  = fmaxf(m[r], mo);
        float a0 = __expf(m[r] - M);
        float a1 = __expf(mo   - M);
        float L  = l[r] * a0 + lo * a1;
        float4 A;
        A.x = acc[r].x * a0 + ao.x * a1;
        A.y = acc[r].y * a0 + ao.y * a1;
        A.z = acc[r].z * a0 + ao.z * a1;
        A.w = acc[r].w * a0 + ao.w * a1;

        if (lane < 32) ((float4*)&lds[wid][r][4])[j] = A;
        if (lane == 0) { lds[wid][r][0] = M; lds[wid][r][1] = L; }
    }
    __syncthreads();

    // cross-wave merge: wave `wid` handles heads r = wid, wid+4
    for (int r = wid; r < GQA_REP; r += 4) {
        float m0 = lds[0][r][0], m1 = lds[1][r][0];
        float m2 = lds[2][r][0], m3 = lds[3][r][0];
        float M = fmaxf(fmaxf(m0, m1), fmaxf(m2, m3));
        float w0 = __expf(m0 - M), w1 = __expf(m1 - M);
        float w2 = __expf(m2 - M), w3 = __expf(m3 - M);
        float L = lds[0][r][1] * w0 + lds[1][r][1] * w1
                + lds[2][r][1] * w2 + lds[3][r][1] * w3;

        float2 a0v = ((const float2*)&lds[0][r][4])[lane];
        float2 a1v = ((const float2*)&lds[1][r][4])[lane];
        float2 a2v = ((const float2*)&lds[2][r][4])[lane];
        float2 a3v = ((const float2*)&lds[3][r][4])[lane];
        float2 a;
        a.x = a0v.x * w0 + a1v.x * w1 + a2v.x * w2 + a3v.x * w3;
        a.y = a0v.y * w0 + a1v.y * w1 + a2v.y * w2 + a3v.y * w3;

        float* rec = ws + WS_PART + ((size_t)(g * UNITS_PER_G + ublk) * GQA_REP + r) * REC;
        ((float2*)(rec + 4))[lane] = a;
        if (lane == 0) { rec[0] = M; rec[1] = L; }
    }
}

// ---------------------------------------------------------------------------
// Kernel 3: combine stage 1 — 12 heads x 32 slabs; each block merges 32 units.
// ---------------------------------------------------------------------------
__global__ __launch_bounds__(64) void combine1(float* __restrict__ ws)
{
    int b  = blockIdx.x;          // 0..383
    int hh = b >> 5;              // head 0..11
    int s  = b & 31;              // slab
    int g = hh / GQA_REP, r = hh % GQA_REP;
    int t  = threadIdx.x;         // 0..63
    int um = t & 31;

    const float* base = ws + WS_PART +
        ((size_t)(g * UNITS_PER_G + s * 32) * GQA_REP + r) * REC;
    const float* rec = base + (size_t)um * GQA_REP * REC;
    float mu = rec[0], lu = rec[1];

    float M = mu;
#pragma unroll
    for (int off = 16; off >= 1; off >>= 1) M = fmaxf(M, __shfl_xor(M, off));
    float w = __expf(mu - M);
    float L = lu * w;
#pragma unroll
    for (int off = 16; off >= 1; off >>= 1) L += __shfl_xor(L, off);

    float2 a; a.x = 0.f; a.y = 0.f;      // dims 2t, 2t+1
    for (int uu = 0; uu < 32; ++uu) {
        float wu = __shfl(w, uu);
        float2 av = ((const float2*)(base + (size_t)uu * GQA_REP * REC + 4))[t];
        a.x += wu * av.x;
        a.y += wu * av.y;
    }
    float* orec = ws + WS_L2 + (size_t)(hh * 32 + s) * REC;
    ((float2*)(orec + 4))[t] = a;
    if (t == 0) { orec[0] = M; orec[1] = L; }
}

// ---------------------------------------------------------------------------
// Kernel 4: combine stage 2 — 12 heads; merge 32 slab records, write out vec.
// ---------------------------------------------------------------------------
__global__ __launch_bounds__(64) void combine2(float* __restrict__ ws)
{
    int hh = blockIdx.x;          // 0..11
    int t  = threadIdx.x;
    int um = t & 31;

    const float* base = ws + WS_L2 + (size_t)(hh * 32) * REC;
    const float* rec  = base + (size_t)um * REC;
    float mu = rec[0], lu = rec[1];

    float M = mu;
#pragma unroll
    for (int off = 16; off >= 1; off >>= 1) M = fmaxf(M, __shfl_xor(M, off));
    float w = __expf(mu - M);
    float L = lu * w;
#pragma unroll
    for (int off = 16; off >= 1; off >>= 1) L += __shfl_xor(L, off);

    float2 a; a.x = 0.f; a.y = 0.f;
    for (int uu = 0; uu < 32; ++uu) {
        float wu = __shfl(w, uu);
        float2 av = ((const float2*)(base + (size_t)uu * REC + 4))[t];
        a.x += wu * av.x;
        a.y += wu * av.y;
    }
    float invL = 1.f / L;
    ws[WS_OUT + hh * HEAD_DIM + 2 * t]     = a.x * invL;
    ws[WS_OUT + hh * HEAD_DIM + 2 * t + 1] = a.y * invL;
}

// ---------------------------------------------------------------------------
// Kernel 5: output projection y = Wo @ out. One row per wave.
// ---------------------------------------------------------------------------
__global__ __launch_bounds__(256) void proj_out(
    const float* __restrict__ Wo, const float* __restrict__ ws,
    float* __restrict__ y)
{
    int r    = (blockIdx.x * 256 + threadIdx.x) >> 6;   // 0..1535
    int lane = threadIdx.x & 63;
    const float4* w4 = (const float4*)(Wo + (size_t)r * HDIM);
    const float4* o4 = (const float4*)(ws + WS_OUT);
    float sum = 0.f;
#pragma unroll
    for (int it = 0; it < 6; ++it) {
        float4 a = w4[lane + 64 * it];
        float4 b = o4[lane + 64 * it];
        sum += a.x * b.x + a.y * b.y + a.z * b.z + a.w * b.w;
    }
#pragma unroll
    for (int off = 32; off >= 1; off >>= 1) sum += __shfl_xor(sum, off);
    if (lane == 0) y[r] = sum;
}

// ---------------------------------------------------------------------------
extern "C" void kernel_launch(void* const* d_in, const int* in_sizes, int n_in,
                              void* d_out, int out_size, void* d_ws, size_t ws_size,
                              hipStream_t stream) {
    const float* x   = (const float*)d_in[0];
    const float* Wq  = (const float*)d_in[1];
    const float* Wk  = (const float*)d_in[2];
    const float* Wv  = (const float*)d_in[3];
    const float* Wo  = (const float*)d_in[4];
    float*       kvk = (float*)d_in[5];
    float*       kvv = (float*)d_in[6];
    const int*   pos = (const int*)d_in[7];
    float* ws = (float*)d_ws;
    float* y  = (float*)d_out;

    proj_qkv   <<<512,  256, 0, stream>>>(x, Wq, Wk, Wv, kvk, kvv, pos, ws);
    attn_decode<<<2048, 256, 0, stream>>>(kvk, kvv, pos, ws);
    combine1   <<<384,   64, 0, stream>>>(ws);
    combine2   <<< 12,   64, 0, stream>>>(ws);
    proj_out   <<<384,  256, 0, stream>>>(Wo, ws, y);
}